// Round 1
// baseline (702.122 us; speedup 1.0000x reference)
//
#include <hip/hip_runtime.h>
#include <math.h>

#define BB   256
#define NPER 256
#define NN   (BB*NPER)      // 65536
#define DEGC 16
#define EE   (NN*DEGC)      // 1048576
#define HH   128
#define LL   3
#define DDIM (HH*LL)        // 384
#define KK   30
#define SPD  385            // padded LDS stride for pooled tile (384 % 32 == 0 -> conflicts)

__global__ void k_zero(int* __restrict__ a, int n) {
    int i = blockIdx.x * blockDim.x + threadIdx.x;
    if (i < n) a[i] = 0;
}

__global__ void k_hist(const int* __restrict__ src, const int* __restrict__ dst,
                       int* __restrict__ deg_out, int* __restrict__ deg_in) {
    int e = blockIdx.x * blockDim.x + threadIdx.x;
    if (e < EE) {
        atomicAdd(&deg_out[src[e]], 1);
        atomicAdd(&deg_in[dst[e]], 1);
    }
}

// one block per graph: exclusive scan of deg_in -> CSR offsets; norms
__global__ void k_scan(const int* __restrict__ deg_in, const int* __restrict__ deg_out,
                       int* __restrict__ off, int* __restrict__ cursor,
                       float* __restrict__ norm_src, float* __restrict__ norm_dst) {
    __shared__ int sc[NPER];
    int t = threadIdx.x, g = blockIdx.x;
    int v = g * NPER + t;
    int di = deg_in[v];
    sc[t] = di;
    __syncthreads();
    for (int ofs = 1; ofs < NPER; ofs <<= 1) {
        int add = (t >= ofs) ? sc[t - ofs] : 0;
        __syncthreads();
        sc[t] += add;
        __syncthreads();
    }
    int o = g * NPER * DEGC + sc[t] - di;   // per-graph edge block base + exclusive scan
    off[v] = o;
    cursor[v] = o;
    norm_dst[v] = rsqrtf((float)max(di, 1));
    norm_src[v] = rsqrtf((float)max(deg_out[v], 1));
}

__global__ void k_csr(const int* __restrict__ dst, const int* __restrict__ src,
                      int* __restrict__ cursor, int* __restrict__ csr) {
    int e = blockIdx.x * blockDim.x + threadIdx.x;
    if (e < EE) {
        int pos = atomicAdd(&cursor[dst[e]], 1);
        csr[pos] = src[e];
    }
}

// gather-form GraphConv layer. 128 threads per node (2 nodes / 256-block).
// writes x[:, layer*H : (layer+1)*H] and per-node max into nmax[layer*N + v].
__global__ void k_layer(int layer,
                        const int* __restrict__ z, const float* __restrict__ zt,
                        float* __restrict__ x,
                        const float* __restrict__ norm_src, const float* __restrict__ norm_dst,
                        const int* __restrict__ off, const int* __restrict__ deg_in,
                        const int* __restrict__ csr,
                        const float* __restrict__ biases, float* __restrict__ nmax) {
    int t = blockIdx.x * blockDim.x + threadIdx.x;
    int v = t >> 7;
    int f = t & (HH - 1);
    int o = off[v], d = deg_in[v];
    float acc = 0.f;
    if (layer == 0) {
        for (int i = 0; i < d; ++i) {
            int s = csr[o + i];
            acc += zt[z[s] * HH + f] * norm_src[s];
        }
    } else {
        const float* xin = x + (size_t)(layer - 1) * HH;
        for (int i = 0; i < d; ++i) {
            int s = csr[o + i];
            acc += xin[(size_t)s * DDIM + f] * norm_src[s];
        }
    }
    float r = tanhf(acc * norm_dst[v] + biases[layer * HH + f]);
    x[(size_t)v * DDIM + layer * HH + f] = r;

    // per-node max over the 128 features (2 waves)
    float m = r;
    for (int s2 = 32; s2 > 0; s2 >>= 1) m = fmaxf(m, __shfl_down(m, s2));
    __shared__ float wmax[4];
    int lane = threadIdx.x & 63;
    int wid  = threadIdx.x >> 6;
    if (lane == 0) wmax[wid] = m;
    __syncthreads();
    if (f == 0) {
        int nib = threadIdx.x >> 7;   // node index within block
        nmax[(size_t)layer * NN + v] = fmaxf(wmax[2 * nib], wmax[2 * nib + 1]);
    }
}

// one block per graph: iterative top-30 argmax (tie -> lower index, like lax.top_k)
__global__ void k_topk(const float* __restrict__ nmax, int* __restrict__ sel) {
    __shared__ float val[NPER];
    __shared__ float rv[NPER];
    __shared__ int   ri[NPER];
    int t = threadIdx.x, g = blockIdx.x;
    int v = g * NPER + t;
    float m = fmaxf(fmaxf(nmax[v], nmax[NN + v]), nmax[2 * NN + v]);
    val[t] = m;
    __syncthreads();
    for (int it = 0; it < KK; ++it) {
        rv[t] = val[t]; ri[t] = t;
        __syncthreads();
        for (int s = NPER / 2; s > 0; s >>= 1) {
            if (t < s) {
                float b2 = rv[t + s]; int ib = ri[t + s];
                if (b2 > rv[t] || (b2 == rv[t] && ib < ri[t])) { rv[t] = b2; ri[t] = ib; }
            }
            __syncthreads();
        }
        int w = ri[0];
        if (t == 0) sel[g * KK + it] = g * NPER + w;
        if (t == w) val[t] = -INFINITY;
        __syncthreads();
    }
}

// one block per selected node: bitonic sort 384 values (padded to 512) ascending
__global__ void k_sort(const int* __restrict__ sel, const float* __restrict__ x,
                       float* __restrict__ pooled) {
    __shared__ float a[512];
    int t = threadIdx.x, bk = blockIdx.x;  // bk = g*K + rank
    int node = sel[bk];
    const float* xr = x + (size_t)node * DDIM;
    for (int i = t; i < 512; i += 256) a[i] = (i < DDIM) ? xr[i] : INFINITY;
    __syncthreads();
    for (int k2 = 2; k2 <= 512; k2 <<= 1) {
        for (int j = k2 >> 1; j > 0; j >>= 1) {
            for (int i = t; i < 512; i += 256) {
                int ixj = i ^ j;
                if (ixj > i) {
                    float x1 = a[i], x2 = a[ixj];
                    bool up = ((i & k2) == 0);
                    if ((x1 > x2) == up) { a[i] = x2; a[ixj] = x1; }
                }
            }
            __syncthreads();
        }
    }
    float* pr = pooled + (size_t)bk * DDIM;
    for (int i = t; i < DDIM; i += 256) pr[i] = a[i];
}

// one block per graph: conv1 -> maxpool -> conv2 -> lin1 -> lin2
__global__ __launch_bounds__(256) void k_head(
        const float* __restrict__ pooled,
        const float* __restrict__ w1, const float* __restrict__ b1,
        const float* __restrict__ w2, const float* __restrict__ b2,
        const float* __restrict__ l1w, const float* __restrict__ l1b,
        const float* __restrict__ l2w, const float* __restrict__ l2b,
        float* __restrict__ out) {
    __shared__ float sp[KK * SPD];     // 30 x 384 padded to 385
    __shared__ float c1s[16 * KK];     // (16,30)
    __shared__ float pp[16 * 15];      // (16,15)
    __shared__ float fl[352];          // (32,11) flattened c*11+t
    __shared__ float h1[HH];
    int t = threadIdx.x, g = blockIdx.x;
    const float* pg = pooled + (size_t)g * KK * DDIM;
    for (int i = t; i < KK * DDIM; i += 256) {
        int k2 = i / DDIM, d2 = i % DDIM;
        sp[k2 * SPD + d2] = pg[i];
    }
    __syncthreads();
    // conv1: c1[o,k] = relu(sum_d sp[k,d]*w1[o,d] + b1[o])
    for (int q = t; q < 16 * KK; q += 256) {
        int o = q / KK, k2 = q % KK;
        const float* wr = w1 + o * DDIM;
        const float* pr = sp + k2 * SPD;
        float acc = b1[o];
        #pragma unroll 8
        for (int d2 = 0; d2 < DDIM; ++d2) acc += pr[d2] * wr[d2];
        c1s[q] = fmaxf(acc, 0.f);
    }
    __syncthreads();
    // maxpool(2,2): p[o,j] = max(c1[o,2j], c1[o,2j+1])
    for (int q = t; q < 16 * 15; q += 256) {
        int o = q / 15, j = q % 15;
        pp[q] = fmaxf(c1s[o * KK + 2 * j], c1s[o * KK + 2 * j + 1]);
    }
    __syncthreads();
    // conv2: fl[c*11+tt] = relu(sum_{i,u} p[i,tt+u]*w2[c,i,u] + b2[c])
    for (int q = t; q < 352; q += 256) {
        int c = q / 11, tt = q % 11;
        float acc = b2[c];
        for (int i = 0; i < 16; ++i) {
            #pragma unroll
            for (int u = 0; u < 5; ++u)
                acc += pp[i * 15 + tt + u] * w2[(c * 16 + i) * 5 + u];
        }
        fl[q] = fmaxf(acc, 0.f);
    }
    __syncthreads();
    // lin1: h1[j] = relu(sum_i fl[i]*l1w[j,i] + l1b[j])
    if (t < HH) {
        const float* wr = l1w + t * 352;
        float acc = l1b[t];
        for (int i = 0; i < 352; ++i) acc += fl[i] * wr[i];
        h1[t] = fmaxf(acc, 0.f);
    }
    __syncthreads();
    // lin2 + bias -> out[g]
    if (t < 64) {
        float v2 = h1[t] * l2w[t] + h1[t + 64] * l2w[t + 64];
        for (int s2 = 32; s2 > 0; s2 >>= 1) v2 += __shfl_down(v2, s2);
        if (t == 0) out[g] = v2 + l2b[0];
    }
}

extern "C" void kernel_launch(void* const* d_in, const int* in_sizes, int n_in,
                              void* d_out, int out_size, void* d_ws, size_t ws_size,
                              hipStream_t stream) {
    const int*   z      = (const int*)d_in[0];
    const int*   src    = (const int*)d_in[1];
    const int*   dst    = (const int*)d_in[2];
    const float* zt     = (const float*)d_in[3];
    const float* biases = (const float*)d_in[4];
    const float* w1     = (const float*)d_in[5];
    const float* b1     = (const float*)d_in[6];
    const float* w2     = (const float*)d_in[7];
    const float* b2     = (const float*)d_in[8];
    const float* l1w    = (const float*)d_in[9];
    const float* l1b    = (const float*)d_in[10];
    const float* l2w    = (const float*)d_in[11];
    const float* l2b    = (const float*)d_in[12];
    float* out = (float*)d_out;

    char* ws = (char*)d_ws;
    size_t ofs = 0;
    auto alloc = [&](size_t bytes) -> void* {
        void* p = ws + ofs;
        ofs += (bytes + 255) & ~(size_t)255;
        return p;
    };
    float* x        = (float*)alloc((size_t)NN * DDIM * 4);   // 96 MB
    float* pooled   = (float*)alloc((size_t)BB * KK * DDIM * 4);
    int*   csr      = (int*)alloc((size_t)EE * 4);
    int*   deg_out  = (int*)alloc((size_t)NN * 4);
    int*   deg_in   = (int*)alloc((size_t)NN * 4);
    int*   off      = (int*)alloc((size_t)NN * 4);
    int*   cursor   = (int*)alloc((size_t)NN * 4);
    float* norm_src = (float*)alloc((size_t)NN * 4);
    float* norm_dst = (float*)alloc((size_t)NN * 4);
    float* nmax     = (float*)alloc((size_t)LL * NN * 4);
    int*   sel      = (int*)alloc((size_t)BB * KK * 4);

    k_zero<<<(NN + 255) / 256, 256, 0, stream>>>(deg_out, NN);
    k_zero<<<(NN + 255) / 256, 256, 0, stream>>>(deg_in, NN);
    k_hist<<<EE / 256, 256, 0, stream>>>(src, dst, deg_out, deg_in);
    k_scan<<<BB, NPER, 0, stream>>>(deg_in, deg_out, off, cursor, norm_src, norm_dst);
    k_csr<<<EE / 256, 256, 0, stream>>>(dst, src, cursor, csr);
    for (int l = 0; l < LL; ++l)
        k_layer<<<NN / 2, 256, 0, stream>>>(l, z, zt, x, norm_src, norm_dst,
                                            off, deg_in, csr, biases, nmax);
    k_topk<<<BB, NPER, 0, stream>>>(nmax, sel);
    k_sort<<<BB * KK, 256, 0, stream>>>(sel, x, pooled);
    k_head<<<BB, 256, 0, stream>>>(pooled, w1, b1, w2, b2, l1w, l1b, l2w, l2b, out);
}

// Round 2
// 335.091 us; speedup vs baseline: 2.0953x; 2.0953x over previous
//
#include <hip/hip_runtime.h>
#include <math.h>

#define BB   256
#define NPER 256
#define NN   (BB*NPER)      // 65536
#define DEGC 16
#define EE   (NN*DEGC)      // 1048576
#define HH   128
#define LL   3
#define DDIM (HH*LL)        // 384
#define KK   30
#define SPD  385            // padded LDS stride for pooled tile
#define CSRB 8192           // padded per-graph CSR bytes

__device__ inline float ftanh(float x) {
    float ax = fabsf(x);
    float e = __expf(-2.f * ax);
    float r = (1.f - e) / (1.f + e);
    return copysignf(r, x);
}

// ---------------- prep: per-graph CSR (u8, 4-aligned lists) + norms ----------------
__global__ __launch_bounds__(256) void k_prep(
        const int* __restrict__ src, const int* __restrict__ dst,
        unsigned char* __restrict__ csr_g, int* __restrict__ offdeg_g,
        float* __restrict__ nsrc_g, float* __restrict__ ndst_g) {
    __shared__ unsigned char ed_s[4096];
    __shared__ unsigned char ed_d[4096];
    __shared__ int degi[NPER], dego[NPER], sc[NPER], cur[NPER];
    __shared__ unsigned char csr_s[CSRB];
    int t = threadIdx.x, g = blockIdx.x;
    degi[t] = 0; dego[t] = 0;
    __syncthreads();
    const int base = g * 4096;
    for (int e = t; e < 4096; e += 256) {
        int s = src[base + e] - g * NPER;   // local 0..255 by construction
        int d = dst[base + e] - g * NPER;
        ed_s[e] = (unsigned char)s;
        ed_d[e] = (unsigned char)d;
        atomicAdd(&dego[s], 1);
        atomicAdd(&degi[d], 1);
    }
    __syncthreads();
    int di = degi[t];
    int pd = (di + 3) & ~3;                 // 4-aligned list length
    sc[t] = pd;
    __syncthreads();
    for (int o = 1; o < NPER; o <<= 1) {
        int a = (t >= o) ? sc[t - o] : 0;
        __syncthreads();
        sc[t] += a;
        __syncthreads();
    }
    int myoff = sc[t] - pd;                 // exclusive scan, 4-aligned
    cur[t] = myoff;
    __syncthreads();
    for (int e = t; e < 4096; e += 256) {
        int d = ed_d[e];
        int pos = atomicAdd(&cur[d], 1);
        csr_s[pos] = ed_s[e];
    }
    __syncthreads();
    offdeg_g[g * NPER + t] = myoff | (di << 16);
    nsrc_g[g * NPER + t] = rsqrtf((float)max(dego[t], 1));
    ndst_g[g * NPER + t] = rsqrtf((float)max(di, 1));
    int4* cg = (int4*)(csr_g + (size_t)g * CSRB);
    const int4* cs = (const int4*)csr_s;
    for (int i = t; i < CSRB / 16; i += 256) cg[i] = cs[i];
}

// ---------------- layer: LDS-tiled gather GraphConv ----------------
// stores x scaled by norm_src (un-scaled at sort); nmax from un-scaled tanh.
__global__ __launch_bounds__(256, 1) void k_layer(
        int l, const int* __restrict__ z, const float* __restrict__ zt,
        const unsigned char* __restrict__ csr_g, const int* __restrict__ offdeg_g,
        const float* __restrict__ nsrc_g, const float* __restrict__ ndst_g,
        const float* __restrict__ biases, float* __restrict__ xall,
        float* __restrict__ nmax3) {
    extern __shared__ char smem[];
    float* hs = (float*)smem;                                   // 256*128*4 = 131072
    unsigned char* csr_s = (unsigned char*)(smem + 131072);     // 8192
    int*   od_s = (int*)(smem + 131072 + 8192);                 // 1024
    float* ns_s = (float*)(smem + 131072 + 8192 + 1024);        // 1024
    float* nd_s = (float*)(smem + 131072 + 8192 + 2048);        // 1024
    int*   z_s  = (int*)(smem + 131072 + 8192 + 3072);          // 1024

    int t = threadIdx.x, g = blockIdx.x;
    int vbase = g * NPER;
    od_s[t] = offdeg_g[vbase + t];
    ns_s[t] = nsrc_g[vbase + t];
    nd_s[t] = ndst_g[vbase + t];
    if (l == 0) z_s[t] = z[vbase + t];
    {
        const int4* cg = (const int4*)(csr_g + (size_t)g * CSRB);
        int4* cs = (int4*)csr_s;
        for (int i = t; i < CSRB / 16; i += 256) cs[i] = cg[i];
    }
    __syncthreads();

    // stage input tile (scaled by norm_src) into hs[256][128]
    if (l == 0) {
        const float4* zt4 = (const float4*)zt;
        float4* h4 = (float4*)hs;
        for (int idx = t; idx < 8192; idx += 256) {
            int row = idx >> 5, c = idx & 31;
            float4 hv = zt4[(size_t)z_s[row] * 32 + c];
            float s = ns_s[row];
            hv.x *= s; hv.y *= s; hv.z *= s; hv.w *= s;
            h4[idx] = hv;
        }
    } else {
        float4* h4 = (float4*)hs;
        const float* xin = xall + (size_t)(l - 1) * HH;
        for (int idx = t; idx < 8192; idx += 256) {
            int row = idx >> 5, c = idx & 31;
            h4[idx] = *(const float4*)&xin[(size_t)(vbase + row) * DDIM + c * 4];
        }
    }
    __syncthreads();

    int f4 = t & 31, grp = t >> 5;          // 8 groups x 32 feature-lanes
    float4 bias = ((const float4*)biases)[l * 32 + f4];
    float* xout = xall + (size_t)l * HH;

    for (int k = 0; k < 32; ++k) {
        int v = grp * 32 + k;
        int od = od_s[v];
        int off = od & 0xffff, deg = od >> 16;
        float4 acc = {0.f, 0.f, 0.f, 0.f};
        for (int i4 = 0; i4 < deg; i4 += 4) {
            unsigned w = *(const unsigned*)(csr_s + off + i4);
            int rem = deg - i4;
            {
                int s = w & 255;
                const float4 hv = ((const float4*)(hs + s * HH))[f4];
                acc.x += hv.x; acc.y += hv.y; acc.z += hv.z; acc.w += hv.w;
            }
            if (rem > 1) {
                int s = (w >> 8) & 255;
                const float4 hv = ((const float4*)(hs + s * HH))[f4];
                acc.x += hv.x; acc.y += hv.y; acc.z += hv.z; acc.w += hv.w;
            }
            if (rem > 2) {
                int s = (w >> 16) & 255;
                const float4 hv = ((const float4*)(hs + s * HH))[f4];
                acc.x += hv.x; acc.y += hv.y; acc.z += hv.z; acc.w += hv.w;
            }
            if (rem > 3) {
                int s = (w >> 24) & 255;
                const float4 hv = ((const float4*)(hs + s * HH))[f4];
                acc.x += hv.x; acc.y += hv.y; acc.z += hv.z; acc.w += hv.w;
            }
        }
        float ndv = nd_s[v], nsv = ns_s[v];
        float4 r;
        r.x = ftanh(acc.x * ndv + bias.x);
        r.y = ftanh(acc.y * ndv + bias.y);
        r.z = ftanh(acc.z * ndv + bias.z);
        r.w = ftanh(acc.w * ndv + bias.w);
        float m = fmaxf(fmaxf(r.x, r.y), fmaxf(r.z, r.w));
        for (int o2 = 16; o2; o2 >>= 1) m = fmaxf(m, __shfl_xor(m, o2, 32));
        if (f4 == 0) nmax3[(size_t)l * NN + vbase + v] = m;
        float4 sc4;
        sc4.x = r.x * nsv; sc4.y = r.y * nsv; sc4.z = r.z * nsv; sc4.w = r.w * nsv;
        *(float4*)&xout[(size_t)(vbase + v) * DDIM + f4 * 4] = sc4;
    }
}

// ---------------- topk: barrier-free rank count ----------------
__global__ __launch_bounds__(256) void k_topk(const float* __restrict__ nmax3,
                                              int* __restrict__ sel) {
    __shared__ float vals[NPER];
    int t = threadIdx.x, g = blockIdx.x, v = g * NPER + t;
    float m = fmaxf(fmaxf(nmax3[v], nmax3[NN + v]), nmax3[2 * NN + v]);
    vals[t] = m;
    __syncthreads();
    int rank = 0;
    for (int u = 0; u < NPER; ++u) {
        float uv = vals[u];
        rank += (uv > m) || (uv == m && u < t);
    }
    if (rank < KK) sel[g * KK + rank] = t;   // local node index
}

// ---------------- sort: bitonic 512 per selected node (un-scales) ----------------
__global__ __launch_bounds__(256) void k_sort(const int* __restrict__ sel,
                                              const float* __restrict__ xall,
                                              const float* __restrict__ nsrc_g,
                                              float* __restrict__ pooled) {
    __shared__ float a[512];
    int t = threadIdx.x, bk = blockIdx.x, g = bk / KK;
    int node = sel[bk];
    int vg = g * NPER + node;
    float inv = 1.f / nsrc_g[vg];
    const float* xr = xall + (size_t)vg * DDIM;
    for (int i = t; i < 512; i += 256) a[i] = (i < DDIM) ? xr[i] * inv : INFINITY;
    __syncthreads();
    for (int k2 = 2; k2 <= 512; k2 <<= 1) {
        for (int j = k2 >> 1; j > 0; j >>= 1) {
            for (int i = t; i < 512; i += 256) {
                int ixj = i ^ j;
                if (ixj > i) {
                    float x1 = a[i], x2 = a[ixj];
                    bool up = ((i & k2) == 0);
                    if ((x1 > x2) == up) { a[i] = x2; a[ixj] = x1; }
                }
            }
            __syncthreads();
        }
    }
    float* pr = pooled + (size_t)bk * DDIM;
    for (int i = t; i < DDIM; i += 256) pr[i] = a[i];
}

// ---------------- head: conv1 -> maxpool -> conv2 -> lin1 -> lin2 ----------------
__global__ __launch_bounds__(256) void k_head(
        const float* __restrict__ pooled,
        const float* __restrict__ w1, const float* __restrict__ b1,
        const float* __restrict__ w2, const float* __restrict__ b2,
        const float* __restrict__ l1w, const float* __restrict__ l1b,
        const float* __restrict__ l2w, const float* __restrict__ l2b,
        float* __restrict__ out) {
    __shared__ float sp[KK * SPD];
    __shared__ float c1s[16 * KK];
    __shared__ float pp[16 * 15];
    __shared__ float fl[352];
    __shared__ float h1[HH];
    int t = threadIdx.x, g = blockIdx.x;
    const float* pg = pooled + (size_t)g * KK * DDIM;
    for (int i = t; i < KK * DDIM; i += 256) {
        int k2 = i / DDIM, d2 = i % DDIM;
        sp[k2 * SPD + d2] = pg[i];
    }
    __syncthreads();
    for (int q = t; q < 16 * KK; q += 256) {
        int o = q / KK, k2 = q % KK;
        const float* wr = w1 + o * DDIM;
        const float* pr = sp + k2 * SPD;
        float acc = b1[o];
        #pragma unroll 8
        for (int d2 = 0; d2 < DDIM; ++d2) acc += pr[d2] * wr[d2];
        c1s[q] = fmaxf(acc, 0.f);
    }
    __syncthreads();
    for (int q = t; q < 16 * 15; q += 256) {
        int o = q / 15, j = q % 15;
        pp[q] = fmaxf(c1s[o * KK + 2 * j], c1s[o * KK + 2 * j + 1]);
    }
    __syncthreads();
    for (int q = t; q < 352; q += 256) {
        int c = q / 11, tt = q % 11;
        float acc = b2[c];
        for (int i = 0; i < 16; ++i) {
            #pragma unroll
            for (int u = 0; u < 5; ++u)
                acc += pp[i * 15 + tt + u] * w2[(c * 16 + i) * 5 + u];
        }
        fl[q] = fmaxf(acc, 0.f);
    }
    __syncthreads();
    if (t < HH) {
        const float* wr = l1w + t * 352;
        float acc = l1b[t];
        for (int i = 0; i < 352; ++i) acc += fl[i] * wr[i];
        h1[t] = fmaxf(acc, 0.f);
    }
    __syncthreads();
    if (t < 64) {
        float v2 = h1[t] * l2w[t] + h1[t + 64] * l2w[t + 64];
        for (int s2 = 32; s2 > 0; s2 >>= 1) v2 += __shfl_down(v2, s2);
        if (t == 0) out[g] = v2 + l2b[0];
    }
}

extern "C" void kernel_launch(void* const* d_in, const int* in_sizes, int n_in,
                              void* d_out, int out_size, void* d_ws, size_t ws_size,
                              hipStream_t stream) {
    const int*   z      = (const int*)d_in[0];
    const int*   src    = (const int*)d_in[1];
    const int*   dst    = (const int*)d_in[2];
    const float* zt     = (const float*)d_in[3];
    const float* biases = (const float*)d_in[4];
    const float* w1     = (const float*)d_in[5];
    const float* b1     = (const float*)d_in[6];
    const float* w2     = (const float*)d_in[7];
    const float* b2     = (const float*)d_in[8];
    const float* l1w    = (const float*)d_in[9];
    const float* l1b    = (const float*)d_in[10];
    const float* l2w    = (const float*)d_in[11];
    const float* l2b    = (const float*)d_in[12];
    float* out = (float*)d_out;

    char* ws = (char*)d_ws;
    size_t ofs = 0;
    auto alloc = [&](size_t bytes) -> void* {
        void* p = ws + ofs;
        ofs += (bytes + 255) & ~(size_t)255;
        return p;
    };
    float* xall     = (float*)alloc((size_t)NN * DDIM * 4);   // 96 MB (scaled)
    float* pooled   = (float*)alloc((size_t)BB * KK * DDIM * 4);
    unsigned char* csr_g = (unsigned char*)alloc((size_t)BB * CSRB);
    int*   offdeg_g = (int*)alloc((size_t)NN * 4);
    float* nsrc_g   = (float*)alloc((size_t)NN * 4);
    float* ndst_g   = (float*)alloc((size_t)NN * 4);
    float* nmax3    = (float*)alloc((size_t)LL * NN * 4);
    int*   sel      = (int*)alloc((size_t)BB * KK * 4);

    const int SMEM = 131072 + 8192 + 3 * 1024 + 1024;  // 143360 B
    static bool attr_set = false;
    hipFuncSetAttribute((const void*)k_layer,
                        hipFuncAttributeMaxDynamicSharedMemorySize, SMEM);
    (void)attr_set;

    k_prep<<<BB, 256, 0, stream>>>(src, dst, csr_g, offdeg_g, nsrc_g, ndst_g);
    for (int l = 0; l < LL; ++l)
        k_layer<<<BB, 256, SMEM, stream>>>(l, z, zt, csr_g, offdeg_g,
                                           nsrc_g, ndst_g, biases, xall, nmax3);
    k_topk<<<BB, 256, 0, stream>>>(nmax3, sel);
    k_sort<<<BB * KK, 256, 0, stream>>>(sel, xall, nsrc_g, pooled);
    k_head<<<BB, 256, 0, stream>>>(pooled, w1, b1, w2, b2, l1w, l1b, l2w, l2b, out);
}

// Round 3
// 202.624 us; speedup vs baseline: 3.4651x; 1.6538x over previous
//
#include <hip/hip_runtime.h>
#include <math.h>

#define BB   256
#define NPER 256
#define NN   (BB*NPER)      // 65536
#define DEGC 16
#define EE   (NN*DEGC)      // 1048576
#define HH   128
#define LL   3
#define DDIM (HH*LL)        // 384
#define KK   30
#define SPD  385            // padded LDS stride for pooled tile
#define CSRB 8192           // padded per-graph CSR bytes

__device__ inline float ftanh(float x) {
    float ax = fabsf(x);
    float e = __expf(-2.f * ax);
    float r = (1.f - e) / (1.f + e);
    return copysignf(r, x);
}

// ---------------- prep: per-graph CSR (u8, 4-aligned lists) + norms ----------------
__global__ __launch_bounds__(256) void k_prep(
        const int* __restrict__ src, const int* __restrict__ dst,
        unsigned char* __restrict__ csr_g, int* __restrict__ offdeg_g,
        float* __restrict__ nsrc_g, float* __restrict__ ndst_g) {
    __shared__ unsigned char ed_s[4096];
    __shared__ unsigned char ed_d[4096];
    __shared__ int degi[NPER], dego[NPER], sc[NPER], cur[NPER];
    __shared__ unsigned char csr_s[CSRB];
    int t = threadIdx.x, g = blockIdx.x;
    degi[t] = 0; dego[t] = 0;
    __syncthreads();
    const int base = g * 4096;
    for (int e = t; e < 4096; e += 256) {
        int s = src[base + e] - g * NPER;   // local 0..255 by construction
        int d = dst[base + e] - g * NPER;
        ed_s[e] = (unsigned char)s;
        ed_d[e] = (unsigned char)d;
        atomicAdd(&dego[s], 1);
        atomicAdd(&degi[d], 1);
    }
    __syncthreads();
    int di = degi[t];
    int pd = (di + 3) & ~3;                 // 4-aligned list length
    sc[t] = pd;
    __syncthreads();
    for (int o = 1; o < NPER; o <<= 1) {
        int a = (t >= o) ? sc[t - o] : 0;
        __syncthreads();
        sc[t] += a;
        __syncthreads();
    }
    int myoff = sc[t] - pd;                 // exclusive scan, 4-aligned
    cur[t] = myoff;
    __syncthreads();
    for (int e = t; e < 4096; e += 256) {
        int d = ed_d[e];
        int pos = atomicAdd(&cur[d], 1);
        csr_s[pos] = ed_s[e];
    }
    __syncthreads();
    offdeg_g[g * NPER + t] = myoff | (di << 16);
    nsrc_g[g * NPER + t] = rsqrtf((float)max(dego[t], 1));
    ndst_g[g * NPER + t] = rsqrtf((float)max(di, 1));
    int4* cg = (int4*)(csr_g + (size_t)g * CSRB);
    const int4* cs = (const int4*)csr_s;
    for (int i = t; i < CSRB / 16; i += 256) cg[i] = cs[i];
}

// ---------------- layer: LDS-tiled gather GraphConv, feature-split x2 ----------------
// block handles 64 features (half). stores x scaled by norm_src; partial nmax per half.
__global__ __launch_bounds__(256, 2) void k_layer(
        int l, const int* __restrict__ z, const float* __restrict__ zt,
        const unsigned char* __restrict__ csr_g, const int* __restrict__ offdeg_g,
        const float* __restrict__ nsrc_g, const float* __restrict__ ndst_g,
        const float* __restrict__ biases, float* __restrict__ xall,
        float* __restrict__ nmaxP) {
    extern __shared__ char smem[];
    float* hs = (float*)smem;                                   // 256*64*4 = 65536
    unsigned char* csr_s = (unsigned char*)(smem + 65536);      // 8192
    int*   od_s = (int*)(smem + 65536 + 8192);                  // 1024
    float* ns_s = (float*)(smem + 65536 + 8192 + 1024);         // 1024
    float* nd_s = (float*)(smem + 65536 + 8192 + 2048);         // 1024
    int*   z_s  = (int*)(smem + 65536 + 8192 + 3072);           // 1024

    int t = threadIdx.x;
    int g = blockIdx.x >> 1, half = blockIdx.x & 1;
    int vbase = g * NPER;
    od_s[t] = offdeg_g[vbase + t];
    ns_s[t] = nsrc_g[vbase + t];
    nd_s[t] = ndst_g[vbase + t];
    if (l == 0) z_s[t] = z[vbase + t];
    {
        const int4* cg = (const int4*)(csr_g + (size_t)g * CSRB);
        int4* cs = (int4*)csr_s;
        for (int i = t; i < CSRB / 16; i += 256) cs[i] = cg[i];
    }
    __syncthreads();

    // stage input half-tile (scaled by norm_src) into hs[256][64]
    if (l == 0) {
        const float4* zt4 = (const float4*)zt;
        float4* h4 = (float4*)hs;
        for (int idx = t; idx < 4096; idx += 256) {
            int row = idx >> 4, c = idx & 15;
            float4 hv = zt4[(size_t)z_s[row] * 32 + half * 16 + c];
            float s = ns_s[row];
            hv.x *= s; hv.y *= s; hv.z *= s; hv.w *= s;
            h4[idx] = hv;
        }
    } else {
        float4* h4 = (float4*)hs;
        const float* xin = xall + (size_t)(l - 1) * HH + half * 64;
        for (int idx = t; idx < 4096; idx += 256) {
            int row = idx >> 4, c = idx & 15;
            h4[idx] = *(const float4*)&xin[(size_t)(vbase + row) * DDIM + c * 4];
        }
    }
    __syncthreads();

    int f4 = t & 15, grp = t >> 4;          // 16 groups x 16 feature-lanes
    float4 bias = ((const float4*)biases)[l * 32 + half * 16 + f4];
    float* xout = xall + (size_t)l * HH + half * 64;

    for (int k = 0; k < 16; ++k) {
        int v = grp * 16 + k;
        int od = od_s[v];
        int off = od & 0xffff, deg = od >> 16;
        float4 acc = {0.f, 0.f, 0.f, 0.f};
        for (int i4 = 0; i4 < deg; i4 += 4) {
            unsigned w = *(const unsigned*)(csr_s + off + i4);
            int rem = deg - i4;
            {
                int s = w & 255;
                const float4 hv = ((const float4*)(hs + s * 64))[f4];
                acc.x += hv.x; acc.y += hv.y; acc.z += hv.z; acc.w += hv.w;
            }
            if (rem > 1) {
                int s = (w >> 8) & 255;
                const float4 hv = ((const float4*)(hs + s * 64))[f4];
                acc.x += hv.x; acc.y += hv.y; acc.z += hv.z; acc.w += hv.w;
            }
            if (rem > 2) {
                int s = (w >> 16) & 255;
                const float4 hv = ((const float4*)(hs + s * 64))[f4];
                acc.x += hv.x; acc.y += hv.y; acc.z += hv.z; acc.w += hv.w;
            }
            if (rem > 3) {
                int s = (w >> 24) & 255;
                const float4 hv = ((const float4*)(hs + s * 64))[f4];
                acc.x += hv.x; acc.y += hv.y; acc.z += hv.z; acc.w += hv.w;
            }
        }
        float ndv = nd_s[v], nsv = ns_s[v];
        float4 r;
        r.x = ftanh(acc.x * ndv + bias.x);
        r.y = ftanh(acc.y * ndv + bias.y);
        r.z = ftanh(acc.z * ndv + bias.z);
        r.w = ftanh(acc.w * ndv + bias.w);
        float m = fmaxf(fmaxf(r.x, r.y), fmaxf(r.z, r.w));
        for (int o2 = 8; o2; o2 >>= 1) m = fmaxf(m, __shfl_xor(m, o2, 16));
        if (f4 == 0) nmaxP[(size_t)(l * 2 + half) * NN + vbase + v] = m;
        float4 sc4;
        sc4.x = r.x * nsv; sc4.y = r.y * nsv; sc4.z = r.z * nsv; sc4.w = r.w * nsv;
        *(float4*)&xout[(size_t)(vbase + v) * DDIM + f4 * 4] = sc4;
    }
}

// ---------------- topk: barrier-free rank count (6 partial maxes) ----------------
__global__ __launch_bounds__(256) void k_topk(const float* __restrict__ nmaxP,
                                              int* __restrict__ sel) {
    __shared__ float vals[NPER];
    int t = threadIdx.x, g = blockIdx.x, v = g * NPER + t;
    float m = nmaxP[v];
    for (int p = 1; p < 6; ++p) m = fmaxf(m, nmaxP[(size_t)p * NN + v]);
    vals[t] = m;
    __syncthreads();
    int rank = 0;
    for (int u = 0; u < NPER; ++u) {
        float uv = vals[u];
        rank += (uv > m) || (uv == m && u < t);
    }
    if (rank < KK) sel[g * KK + rank] = t;   // local node index
}

// ---------------- sort: register bitonic 512, one wave per row ----------------
#define CSW(a, b, u) { float lo = fminf(v[a], v[b]), hi = fmaxf(v[a], v[b]); \
                       v[a] = (u) ? lo : hi; v[b] = (u) ? hi : lo; }

__global__ __launch_bounds__(256) void k_sort(const int* __restrict__ sel,
                                              const float* __restrict__ xall,
                                              const float* __restrict__ nsrc_g,
                                              float* __restrict__ pooled) {
    int t = threadIdx.x;
    int lane = t & 63;
    int wid = t >> 6;
    int bk = blockIdx.x * 4 + wid;          // row id 0..7679
    int g = bk / KK;
    int node = sel[bk];
    int vg = g * NPER + node;
    float inv = 1.f / nsrc_g[vg];
    const float* xr = xall + (size_t)vg * DDIM;
    float v[8];
    int e0 = lane * 8;
    if (e0 < DDIM) {
        float4 a4 = *(const float4*)&xr[e0];
        float4 b4 = *(const float4*)&xr[e0 + 4];
        v[0] = a4.x * inv; v[1] = a4.y * inv; v[2] = a4.z * inv; v[3] = a4.w * inv;
        v[4] = b4.x * inv; v[5] = b4.y * inv; v[6] = b4.z * inv; v[7] = b4.w * inv;
    } else {
        #pragma unroll
        for (int r = 0; r < 8; ++r) v[r] = INFINITY;
    }
    // k2 = 2
    CSW(0,1,true) CSW(2,3,false) CSW(4,5,true) CSW(6,7,false)
    // k2 = 4
    CSW(0,2,true) CSW(1,3,true) CSW(4,6,false) CSW(5,7,false)
    CSW(0,1,true) CSW(2,3,true) CSW(4,5,false) CSW(6,7,false)
    // k2 = 8
    {
        bool u8 = ((lane & 1) == 0);
        CSW(0,4,u8) CSW(1,5,u8) CSW(2,6,u8) CSW(3,7,u8)
        CSW(0,2,u8) CSW(1,3,u8) CSW(4,6,u8) CSW(5,7,u8)
        CSW(0,1,u8) CSW(2,3,u8) CSW(4,5,u8) CSW(6,7,u8)
    }
    // k2 = 16 .. 512
    for (int k2 = 16; k2 <= 512; k2 <<= 1) {
        bool up = ((lane & (k2 >> 3)) == 0);
        for (int j = k2 >> 1; j >= 8; j >>= 1) {
            int d = j >> 3;
            bool keepmin = (((lane & d) == 0) == up);
            #pragma unroll
            for (int r = 0; r < 8; ++r) {
                float pv = __shfl_xor(v[r], d, 64);
                v[r] = keepmin ? fminf(v[r], pv) : fmaxf(v[r], pv);
            }
        }
        CSW(0,4,up) CSW(1,5,up) CSW(2,6,up) CSW(3,7,up)
        CSW(0,2,up) CSW(1,3,up) CSW(4,6,up) CSW(5,7,up)
        CSW(0,1,up) CSW(2,3,up) CSW(4,5,up) CSW(6,7,up)
    }
    if (e0 < DDIM) {
        float* pr = pooled + (size_t)bk * DDIM + e0;
        *(float4*)pr = make_float4(v[0], v[1], v[2], v[3]);
        *(float4*)(pr + 4) = make_float4(v[4], v[5], v[6], v[7]);
    }
}

// ---------------- head: conv1 -> maxpool -> conv2 -> lin1 -> lin2 ----------------
__global__ __launch_bounds__(256) void k_head(
        const float* __restrict__ pooled,
        const float* __restrict__ w1, const float* __restrict__ b1,
        const float* __restrict__ w2, const float* __restrict__ b2,
        const float* __restrict__ l1w, const float* __restrict__ l1b,
        const float* __restrict__ l2w, const float* __restrict__ l2b,
        float* __restrict__ out) {
    __shared__ float sp[KK * SPD];
    __shared__ float c1s[16 * KK];
    __shared__ float pp[16 * 15];
    __shared__ float fl[352];
    __shared__ float h1[HH];
    int t = threadIdx.x, g = blockIdx.x;
    const float* pg = pooled + (size_t)g * KK * DDIM;
    for (int i = t; i < KK * DDIM; i += 256) {
        int k2 = i / DDIM, d2 = i % DDIM;
        sp[k2 * SPD + d2] = pg[i];
    }
    __syncthreads();
    for (int q = t; q < 16 * KK; q += 256) {
        int o = q / KK, k2 = q % KK;
        const float* wr = w1 + o * DDIM;
        const float* pr = sp + k2 * SPD;
        float acc = b1[o];
        #pragma unroll 8
        for (int d2 = 0; d2 < DDIM; ++d2) acc += pr[d2] * wr[d2];
        c1s[q] = fmaxf(acc, 0.f);
    }
    __syncthreads();
    for (int q = t; q < 16 * 15; q += 256) {
        int o = q / 15, j = q % 15;
        pp[q] = fmaxf(c1s[o * KK + 2 * j], c1s[o * KK + 2 * j + 1]);
    }
    __syncthreads();
    for (int q = t; q < 352; q += 256) {
        int c = q / 11, tt = q % 11;
        float acc = b2[c];
        for (int i = 0; i < 16; ++i) {
            #pragma unroll
            for (int u = 0; u < 5; ++u)
                acc += pp[i * 15 + tt + u] * w2[(c * 16 + i) * 5 + u];
        }
        fl[q] = fmaxf(acc, 0.f);
    }
    __syncthreads();
    if (t < HH) {
        const float* wr = l1w + t * 352;
        float acc = l1b[t];
        for (int i = 0; i < 352; ++i) acc += fl[i] * wr[i];
        h1[t] = fmaxf(acc, 0.f);
    }
    __syncthreads();
    if (t < 64) {
        float v2 = h1[t] * l2w[t] + h1[t + 64] * l2w[t + 64];
        for (int s2 = 32; s2 > 0; s2 >>= 1) v2 += __shfl_down(v2, s2);
        if (t == 0) out[g] = v2 + l2b[0];
    }
}

extern "C" void kernel_launch(void* const* d_in, const int* in_sizes, int n_in,
                              void* d_out, int out_size, void* d_ws, size_t ws_size,
                              hipStream_t stream) {
    const int*   z      = (const int*)d_in[0];
    const int*   src    = (const int*)d_in[1];
    const int*   dst    = (const int*)d_in[2];
    const float* zt     = (const float*)d_in[3];
    const float* biases = (const float*)d_in[4];
    const float* w1     = (const float*)d_in[5];
    const float* b1     = (const float*)d_in[6];
    const float* w2     = (const float*)d_in[7];
    const float* b2     = (const float*)d_in[8];
    const float* l1w    = (const float*)d_in[9];
    const float* l1b    = (const float*)d_in[10];
    const float* l2w    = (const float*)d_in[11];
    const float* l2b    = (const float*)d_in[12];
    float* out = (float*)d_out;

    char* ws = (char*)d_ws;
    size_t ofs = 0;
    auto alloc = [&](size_t bytes) -> void* {
        void* p = ws + ofs;
        ofs += (bytes + 255) & ~(size_t)255;
        return p;
    };
    float* xall     = (float*)alloc((size_t)NN * DDIM * 4);   // 96 MB (scaled)
    float* pooled   = (float*)alloc((size_t)BB * KK * DDIM * 4);
    unsigned char* csr_g = (unsigned char*)alloc((size_t)BB * CSRB);
    int*   offdeg_g = (int*)alloc((size_t)NN * 4);
    float* nsrc_g   = (float*)alloc((size_t)NN * 4);
    float* ndst_g   = (float*)alloc((size_t)NN * 4);
    float* nmaxP    = (float*)alloc((size_t)2 * LL * NN * 4);
    int*   sel      = (int*)alloc((size_t)BB * KK * 4);

    const int SMEM = 65536 + 8192 + 4 * 1024;  // 77824 B
    hipFuncSetAttribute((const void*)k_layer,
                        hipFuncAttributeMaxDynamicSharedMemorySize, SMEM);

    k_prep<<<BB, 256, 0, stream>>>(src, dst, csr_g, offdeg_g, nsrc_g, ndst_g);
    for (int l = 0; l < LL; ++l)
        k_layer<<<2 * BB, 256, SMEM, stream>>>(l, z, zt, csr_g, offdeg_g,
                                               nsrc_g, ndst_g, biases, xall, nmaxP);
    k_topk<<<BB, 256, 0, stream>>>(nmaxP, sel);
    k_sort<<<BB * KK / 4, 256, 0, stream>>>(sel, xall, nsrc_g, pooled);
    k_head<<<BB, 256, 0, stream>>>(pooled, w1, b1, w2, b2, l1w, l1b, l2w, l2b, out);
}

// Round 4
// 126.552 us; speedup vs baseline: 5.5481x; 1.6011x over previous
//
#include <hip/hip_runtime.h>
#include <math.h>

#define BB   256
#define NPER 256
#define NN   (BB*NPER)      // 65536
#define HH   128
#define DDIM 384
#define KK   30
#define SPD  388            // sorted-row stride (floats); 1552 B, 16B-aligned, rows phase-shift 16B
#define SMEM_SZ 148480

__device__ inline float ftanh(float x) {
    float ax = fabsf(x);
    float e = __expf(-2.f * ax);
    float r = (1.f - e) / (1.f + e);
    return copysignf(r, x);
}

// One block per graph. 1024 threads = 32 node-slots x 32 feature-float4-lanes.
__global__ __launch_bounds__(1024) void k_fused(
        const int* __restrict__ z, const int* __restrict__ src, const int* __restrict__ dst,
        const float* __restrict__ zt, const float* __restrict__ biases,
        const float* __restrict__ w1, const float* __restrict__ b1,
        const float* __restrict__ w2, const float* __restrict__ b2,
        const float* __restrict__ l1w, const float* __restrict__ l1b,
        const float* __restrict__ l2w, const float* __restrict__ l2b,
        float* __restrict__ x, float* __restrict__ out) {
    extern __shared__ char smem[];
    float* tile = (float*)smem;                                  // 131072 B (reused later: sp + head scratch)
    unsigned char* csr_s = (unsigned char*)(smem + 131072);      // 8192 B
    char* meta = smem + 139264;
    int*   od_s = (int*)meta;                                    // 256 ints
    float* ns_s = (float*)(meta + 1024);
    float* nd_s = (float*)(meta + 2048);
    float* nm   = (float*)(meta + 3072);
    int*   rnk  = (int*)(meta + 4096);
    int*   scr  = (int*)(meta + 5120);                           // 4096 B scratch

    const int t = threadIdx.x, g = blockIdx.x, vbase = g * NPER;
    const int f4 = t & 31, w = t >> 5;

    // ---------------- phase 0: CSR build (edges staged in tile area) ----------------
    int* degi = scr;            // 256
    int* dego = scr + 256;      // 256
    int* cur  = scr + 512;      // 256
    if (t < 256) { degi[t] = 0; dego[t] = 0; }
    __syncthreads();
    unsigned char* ed_s = (unsigned char*)tile;
    unsigned char* ed_d = ed_s + 4096;
    for (int e = t; e < 4096; e += 1024) {
        int s = src[g * 4096 + e] - vbase;   // local 0..255 by construction
        int d = dst[g * 4096 + e] - vbase;
        ed_s[e] = (unsigned char)s;
        ed_d[e] = (unsigned char)d;
        atomicAdd(&dego[s], 1);
        atomicAdd(&degi[d], 1);
    }
    __syncthreads();
    if (t < 256) cur[t] = (degi[t] + 3) & ~3;     // padded list length
    __syncthreads();
    for (int o = 1; o < 256; o <<= 1) {
        int a = 0;
        if (t < 256 && t >= o) a = cur[t - o];
        __syncthreads();
        if (t < 256) cur[t] += a;
        __syncthreads();
    }
    if (t < 256) {
        int di = degi[t];
        int myoff = cur[t] - ((di + 3) & ~3);     // exclusive scan, 4-aligned
        od_s[t] = myoff | (di << 16);
        ns_s[t] = rsqrtf((float)max(dego[t], 1));
        nd_s[t] = rsqrtf((float)max(di, 1));
        cur[t] = myoff;
    }
    __syncthreads();
    for (int e = t; e < 4096; e += 1024) {
        int d = ed_d[e];
        int pos = atomicAdd(&cur[d], 1);
        csr_s[pos] = ed_s[e];
    }
    __syncthreads();

    // ---------------- phase 1: stage layer-0 input (h0 = zt[z] * ns) ----------------
    float4* tile4 = (float4*)tile;
    const float4* zt4 = (const float4*)zt;
    #pragma unroll
    for (int k = 0; k < 8; ++k) {
        int n = k * 32 + w;
        float s = ns_s[n];
        float4 hv = zt4[(size_t)z[vbase + n] * 32 + f4];
        hv.x *= s; hv.y *= s; hv.z *= s; hv.w *= s;
        tile4[n * 32 + f4] = hv;
    }
    __syncthreads();

    // ---------------- phase 2: 3 GraphConv layers, tile-to-tile ----------------
    for (int l = 0; l < 3; ++l) {
        float4 rs[8];
        float4 bias = ((const float4*)biases)[l * 32 + f4];
        #pragma unroll
        for (int k = 0; k < 8; ++k) {
            int v = k * 32 + w;
            int od = od_s[v];
            int off = od & 0xffff, deg = od >> 16;
            float4 acc = {0.f, 0.f, 0.f, 0.f};
            const float4* tb = tile4 + f4;
            for (int i4 = 0; i4 < deg; i4 += 4) {
                unsigned pk = *(const unsigned*)(csr_s + off + i4);
                int rem = deg - i4;
                {
                    float4 hv = tb[(pk & 255) * 32];
                    acc.x += hv.x; acc.y += hv.y; acc.z += hv.z; acc.w += hv.w;
                }
                if (rem > 1) {
                    float4 hv = tb[((pk >> 8) & 255) * 32];
                    acc.x += hv.x; acc.y += hv.y; acc.z += hv.z; acc.w += hv.w;
                }
                if (rem > 2) {
                    float4 hv = tb[((pk >> 16) & 255) * 32];
                    acc.x += hv.x; acc.y += hv.y; acc.z += hv.z; acc.w += hv.w;
                }
                if (rem > 3) {
                    float4 hv = tb[((pk >> 24) & 255) * 32];
                    acc.x += hv.x; acc.y += hv.y; acc.z += hv.z; acc.w += hv.w;
                }
            }
            float ndv = nd_s[v];
            float4 r;
            r.x = ftanh(acc.x * ndv + bias.x);
            r.y = ftanh(acc.y * ndv + bias.y);
            r.z = ftanh(acc.z * ndv + bias.z);
            r.w = ftanh(acc.w * ndv + bias.w);
            // unscaled x to global (only selected rows are read back)
            *(float4*)&x[(size_t)(vbase + v) * DDIM + l * HH + f4 * 4] = r;
            // per-node max: reduce across the 32 feature-lanes (half-wave)
            float m = fmaxf(fmaxf(r.x, r.y), fmaxf(r.z, r.w));
            for (int o2 = 16; o2; o2 >>= 1) m = fmaxf(m, __shfl_xor(m, o2, 32));
            if (f4 == 0) nm[v] = (l == 0) ? m : fmaxf(nm[v], m);
            rs[k] = r;
        }
        __syncthreads();                      // all gathers done before tile overwrite
        if (l < 2) {
            #pragma unroll
            for (int k = 0; k < 8; ++k) {
                int v = k * 32 + w;
                float s = ns_s[v];
                float4 r = rs[k];
                r.x *= s; r.y *= s; r.z *= s; r.w *= s;
                tile4[v * 32 + f4] = r;
            }
            __syncthreads();
        }
    }

    // ---------------- phase 3: top-30 by rank count (parallel partials) ----------------
    {
        int n = t & 255, q = t >> 8;
        float mv = nm[n];
        int p = 0;
        for (int u = q * 64; u < q * 64 + 64; ++u) {
            float uv = nm[u];
            p += (uv > mv) || (uv == mv && u < n);
        }
        scr[t] = p;
    }
    __syncthreads();
    if (t < 256) {
        int rank = scr[t] + scr[t + 256] + scr[t + 512] + scr[t + 768];
        rnk[t] = (rank < KK) ? rank : -1;
    }
    __syncthreads();

    // ---------------- phase 4: gather selected rows into sp (tile reuse) ----------------
    #pragma unroll
    for (int k = 0; k < 8; ++k) {
        int n = k * 32 + w;
        int r = rnk[n];
        if (r >= 0) {
            const float4* xr = (const float4*)&x[(size_t)(vbase + n) * DDIM];  // own stores
            float* srow = tile + r * SPD;
            #pragma unroll
            for (int l = 0; l < 3; ++l)
                *(float4*)&srow[l * HH + f4 * 4] = xr[l * 32 + f4];
        }
    }
    __syncthreads();

    // ---------------- phase 5: register bitonic sort of each selected row ----------------
    {
        int lane = t & 63, wid = t >> 6;
        for (int rr = wid; rr < KK; rr += 16) {
            float* row = tile + rr * SPD;
            float v[8];
            int e0 = lane * 8;
            if (e0 < DDIM) {
                float4 a4 = *(const float4*)&row[e0];
                float4 b4 = *(const float4*)&row[e0 + 4];
                v[0] = a4.x; v[1] = a4.y; v[2] = a4.z; v[3] = a4.w;
                v[4] = b4.x; v[5] = b4.y; v[6] = b4.z; v[7] = b4.w;
            } else {
                #pragma unroll
                for (int r2 = 0; r2 < 8; ++r2) v[r2] = INFINITY;
            }
            #define CSW(a, b, u) { float lo = fminf(v[a], v[b]), hi = fmaxf(v[a], v[b]); \
                                   v[a] = (u) ? lo : hi; v[b] = (u) ? hi : lo; }
            CSW(0,1,true) CSW(2,3,false) CSW(4,5,true) CSW(6,7,false)
            CSW(0,2,true) CSW(1,3,true) CSW(4,6,false) CSW(5,7,false)
            CSW(0,1,true) CSW(2,3,true) CSW(4,5,false) CSW(6,7,false)
            {
                bool u8 = ((lane & 1) == 0);
                CSW(0,4,u8) CSW(1,5,u8) CSW(2,6,u8) CSW(3,7,u8)
                CSW(0,2,u8) CSW(1,3,u8) CSW(4,6,u8) CSW(5,7,u8)
                CSW(0,1,u8) CSW(2,3,u8) CSW(4,5,u8) CSW(6,7,u8)
            }
            for (int k2 = 16; k2 <= 512; k2 <<= 1) {
                bool up = ((lane & (k2 >> 3)) == 0);
                for (int j = k2 >> 1; j >= 8; j >>= 1) {
                    int d = j >> 3;
                    bool keepmin = (((lane & d) == 0) == up);
                    #pragma unroll
                    for (int r2 = 0; r2 < 8; ++r2) {
                        float pv = __shfl_xor(v[r2], d, 64);
                        v[r2] = keepmin ? fminf(v[r2], pv) : fmaxf(v[r2], pv);
                    }
                }
                CSW(0,4,up) CSW(1,5,up) CSW(2,6,up) CSW(3,7,up)
                CSW(0,2,up) CSW(1,3,up) CSW(4,6,up) CSW(5,7,up)
                CSW(0,1,up) CSW(2,3,up) CSW(4,5,up) CSW(6,7,up)
            }
            #undef CSW
            if (e0 < DDIM) {
                *(float4*)&row[e0] = make_float4(v[0], v[1], v[2], v[3]);
                *(float4*)&row[e0 + 4] = make_float4(v[4], v[5], v[6], v[7]);
            }
        }
    }
    __syncthreads();

    // ---------------- phase 6: head (conv1 -> maxpool -> conv2 -> lin1 -> lin2) ----------------
    float* c1s = tile + KK * SPD;      // 480 floats
    float* pp  = c1s + 16 * KK;        // 240
    float* fl  = pp + 240;             // 352
    float* h1  = fl + 352;             // 128
    if (t < 480) {                     // o = t&15 broadcast-friendly; k2 = t>>4
        int o = t & 15, k2 = t >> 4;
        const float4* wr = (const float4*)(w1 + o * DDIM);
        const float4* pr = (const float4*)(tile + k2 * SPD);
        float acc = b1[o];
        #pragma unroll 4
        for (int d4 = 0; d4 < 96; ++d4) {
            float4 a = pr[d4], b = wr[d4];
            acc += a.x * b.x + a.y * b.y + a.z * b.z + a.w * b.w;
        }
        c1s[o * KK + k2] = fmaxf(acc, 0.f);
    }
    __syncthreads();
    if (t < 240) {
        int o = t / 15, j = t % 15;
        pp[t] = fmaxf(c1s[o * KK + 2 * j], c1s[o * KK + 2 * j + 1]);
    }
    __syncthreads();
    if (t < 352) {
        int c = t / 11, tt = t % 11;
        float acc = b2[c];
        for (int i = 0; i < 16; ++i) {
            #pragma unroll
            for (int u = 0; u < 5; ++u)
                acc += pp[i * 15 + tt + u] * w2[(c * 16 + i) * 5 + u];
        }
        fl[t] = fmaxf(acc, 0.f);
    }
    __syncthreads();
    if (t < 128) {
        const float4* wr = (const float4*)(l1w + t * 352);
        const float4* fr = (const float4*)fl;
        float acc = l1b[t];
        #pragma unroll 4
        for (int i = 0; i < 88; ++i) {
            float4 a = fr[i], b = wr[i];
            acc += a.x * b.x + a.y * b.y + a.z * b.z + a.w * b.w;
        }
        h1[t] = fmaxf(acc, 0.f);
    }
    __syncthreads();
    if (t < 64) {
        float v2 = h1[t] * l2w[t] + h1[t + 64] * l2w[t + 64];
        for (int s2 = 32; s2 > 0; s2 >>= 1) v2 += __shfl_down(v2, s2);
        if (t == 0) out[g] = v2 + l2b[0];
    }
}

extern "C" void kernel_launch(void* const* d_in, const int* in_sizes, int n_in,
                              void* d_out, int out_size, void* d_ws, size_t ws_size,
                              hipStream_t stream) {
    const int*   z      = (const int*)d_in[0];
    const int*   src    = (const int*)d_in[1];
    const int*   dst    = (const int*)d_in[2];
    const float* zt     = (const float*)d_in[3];
    const float* biases = (const float*)d_in[4];
    const float* w1     = (const float*)d_in[5];
    const float* b1     = (const float*)d_in[6];
    const float* w2     = (const float*)d_in[7];
    const float* b2     = (const float*)d_in[8];
    const float* l1w    = (const float*)d_in[9];
    const float* l1b    = (const float*)d_in[10];
    const float* l2w    = (const float*)d_in[11];
    const float* l2b    = (const float*)d_in[12];
    float* out = (float*)d_out;
    float* x   = (float*)d_ws;   // NN * DDIM f32 = 96 MB

    hipFuncSetAttribute((const void*)k_fused,
                        hipFuncAttributeMaxDynamicSharedMemorySize, SMEM_SZ);

    k_fused<<<BB, 1024, SMEM_SZ, stream>>>(z, src, dst, zt, biases,
                                           w1, b1, w2, b2, l1w, l1b, l2w, l2b,
                                           x, out);
}